// Round 1
// baseline (517.291 us; speedup 1.0000x reference)
//
#include <hip/hip_runtime.h>
#include <stdint.h>

typedef __bf16 bf16;
typedef __attribute__((ext_vector_type(8))) __bf16 bf16x8;
typedef __attribute__((ext_vector_type(4))) float f32x4;

// Problem dims (fixed)
constexpr int S = 2048;
constexpr int D = 1024;
constexpr int H = 16;
constexpr int DH = 64;
constexpr int M = 4096;  // B*S

// ------------------------- split-bf16 GEMM -------------------------
// C[M,1024] = A[M,1024] @ W[1024,1024] + bias
// A fp32 split into hi/lo bf16; 3 MFMAs per tile-pair => ~fp19 precision.
constexpr int BM = 64, BN = 64, BK = 32;
constexpr int LDT = BK + 8;  // 40 elems = 80B row stride (16B-aligned)

template <int OUT_MODE>  // 0: fp32 row-major out; 1: bf16 out in [B,H,S,DH]
__global__ __launch_bounds__(256) void gemm_split(
    const float* __restrict__ A, const float* __restrict__ W,
    const float* __restrict__ bias, void* __restrict__ out) {
  __shared__ bf16 Ah[BM * LDT], Al[BM * LDT];
  __shared__ bf16 Bh[BN * LDT], Bl[BN * LDT];

  const int tid = threadIdx.x;
  const int bn = blockIdx.x * BN;
  const int bm = blockIdx.y * BM;
  const int wv = tid >> 6;
  const int lane = tid & 63;
  const int quad = lane >> 4;
  const int lo = lane & 15;
  const int wm = (wv >> 1) * 32;
  const int wn = (wv & 1) * 32;

  f32x4 acc[2][2];
#pragma unroll
  for (int i = 0; i < 2; i++)
#pragma unroll
    for (int j = 0; j < 2; j++) acc[i][j] = {0.f, 0.f, 0.f, 0.f};

  const int ar = tid >> 2;         // A stage: row 0..63
  const int ak = (tid & 3) * 8;    // A stage: k offset
  const int bnn = tid & 63;        // B stage: n 0..63
  const int bk0 = (tid >> 6) * 8;  // B stage: k offset

  for (int kt = 0; kt < 1024 / BK; ++kt) {
    {  // stage A tile -> hi/lo
      const float* ap = A + (size_t)(bm + ar) * 1024 + kt * BK + ak;
      f32x4 a0 = *(const f32x4*)ap;
      f32x4 a1 = *(const f32x4*)(ap + 4);
      bf16x8 h, l;
#pragma unroll
      for (int j = 0; j < 4; j++) {
        float v0 = a0[j];
        bf16 h0 = (bf16)v0;
        h[j] = h0;
        l[j] = (bf16)(v0 - (float)h0);
        float v1 = a1[j];
        bf16 h1 = (bf16)v1;
        h[j + 4] = h1;
        l[j + 4] = (bf16)(v1 - (float)h1);
      }
      *(bf16x8*)&Ah[ar * LDT + ak] = h;
      *(bf16x8*)&Al[ar * LDT + ak] = l;
    }
    {  // stage B tile transposed ([n][k]) -> hi/lo
      const float* wp = W + (size_t)(kt * BK + bk0) * 1024 + bn + bnn;
      bf16x8 h, l;
#pragma unroll
      for (int j = 0; j < 8; j++) {
        float v0 = wp[(size_t)j * 1024];
        bf16 h0 = (bf16)v0;
        h[j] = h0;
        l[j] = (bf16)(v0 - (float)h0);
      }
      *(bf16x8*)&Bh[bnn * LDT + bk0] = h;
      *(bf16x8*)&Bl[bnn * LDT + bk0] = l;
    }
    __syncthreads();

    bf16x8 afh[2], afl[2], bfh[2], bfl[2];
#pragma unroll
    for (int mi = 0; mi < 2; mi++) {
      afh[mi] = *(const bf16x8*)&Ah[(wm + mi * 16 + lo) * LDT + quad * 8];
      afl[mi] = *(const bf16x8*)&Al[(wm + mi * 16 + lo) * LDT + quad * 8];
    }
#pragma unroll
    for (int ni = 0; ni < 2; ni++) {
      bfh[ni] = *(const bf16x8*)&Bh[(wn + ni * 16 + lo) * LDT + quad * 8];
      bfl[ni] = *(const bf16x8*)&Bl[(wn + ni * 16 + lo) * LDT + quad * 8];
    }
#pragma unroll
    for (int mi = 0; mi < 2; mi++)
#pragma unroll
      for (int ni = 0; ni < 2; ni++) {
        acc[mi][ni] = __builtin_amdgcn_mfma_f32_16x16x32_bf16(
            afh[mi], bfh[ni], acc[mi][ni], 0, 0, 0);
        acc[mi][ni] = __builtin_amdgcn_mfma_f32_16x16x32_bf16(
            afh[mi], bfl[ni], acc[mi][ni], 0, 0, 0);
        acc[mi][ni] = __builtin_amdgcn_mfma_f32_16x16x32_bf16(
            afl[mi], bfh[ni], acc[mi][ni], 0, 0, 0);
      }
    __syncthreads();
  }

#pragma unroll
  for (int mi = 0; mi < 2; mi++)
#pragma unroll
    for (int ni = 0; ni < 2; ni++) {
      int col = bn + wn + ni * 16 + lo;
      float bv = bias[col];
#pragma unroll
      for (int r = 0; r < 4; r++) {
        int row = bm + wm + mi * 16 + quad * 4 + r;
        float v = acc[mi][ni][r] + bv;
        if (OUT_MODE == 0) {
          ((float*)out)[(size_t)row * 1024 + col] = v;
        } else {
          int b = row >> 11, s = row & (S - 1);
          int h = col >> 6, dh = col & (DH - 1);
          ((bf16*)out)[((((size_t)b * H + h) * S + s) << 6) + dh] = (bf16)v;
        }
      }
    }
}

// ------------------------- flash attention -------------------------
// Q,K,V bf16 [B*H, S, 64]; mask int32 [S,S]; out fp32 [B, S, D].
// Block: 64 q-rows of one (b,h). 4 waves, wave w owns q rows w*16..w*16+15.
constexpr int LDV = 72;  // 144B row stride, 16B-aligned

__global__ __launch_bounds__(256) void attn_kernel(
    const bf16* __restrict__ Qg, const bf16* __restrict__ Kg,
    const bf16* __restrict__ Vg, const int* __restrict__ mask,
    float* __restrict__ Og) {
  __shared__ bf16 Vt[64 * LDV];  // V tile transposed: [dh][key]
  __shared__ bf16 Ps[64 * LDV];  // P tile: [q][key]

  const int qt = blockIdx.x;  // 0..31 q-tile
  const int bh = blockIdx.y;  // 0..31
  const int tid = threadIdx.x;
  const int wv = tid >> 6;
  const int lane = tid & 63;
  const int quad = lane >> 4;
  const int lo = lane & 15;
  const size_t base = (size_t)bh * S * DH;

  // preload Q A-frags (16 rows per wave, K-dim = 64 => 2 frags)
  bf16x8 qf[2];
  {
    const bf16* qp = Qg + base + (size_t)(qt * 64 + wv * 16 + lo) * DH + quad * 8;
    qf[0] = *(const bf16x8*)qp;
    qf[1] = *(const bf16x8*)(qp + 32);
  }

  f32x4 Oacc[4];
#pragma unroll
  for (int i = 0; i < 4; i++) Oacc[i] = {0.f, 0.f, 0.f, 0.f};
  float m_i[4], l_i[4];
#pragma unroll
  for (int r = 0; r < 4; r++) {
    m_i[r] = -INFINITY;
    l_i[r] = 0.f;
  }

  const int vkey = tid & 63;
  const int vdg = tid >> 6;
  const int rowb = qt * 64 + wv * 16 + quad * 4;

  for (int kt = 0; kt < S / 64; ++kt) {
    {  // stage V tile transposed into LDS
      const bf16* vp = Vg + base + (size_t)(kt * 64 + vkey) * DH + vdg * 16;
      bf16x8 v0 = *(const bf16x8*)vp;
      bf16x8 v1 = *(const bf16x8*)(vp + 8);
#pragma unroll
      for (int j = 0; j < 8; j++) Vt[(vdg * 16 + j) * LDV + vkey] = v0[j];
#pragma unroll
      for (int j = 0; j < 8; j++) Vt[(vdg * 16 + 8 + j) * LDV + vkey] = v1[j];
    }

    // scores: S = Q K^T  (K B-frags straight from global; L2-resident)
    f32x4 sacc[4];
#pragma unroll
    for (int ni = 0; ni < 4; ni++) sacc[ni] = {0.f, 0.f, 0.f, 0.f};
#pragma unroll
    for (int ni = 0; ni < 4; ni++) {
      const bf16* kp = Kg + base + (size_t)(kt * 64 + ni * 16 + lo) * DH + quad * 8;
      bf16x8 b0 = *(const bf16x8*)kp;
      bf16x8 b1 = *(const bf16x8*)(kp + 32);
      sacc[ni] = __builtin_amdgcn_mfma_f32_16x16x32_bf16(qf[0], b0, sacc[ni], 0, 0, 0);
      sacc[ni] = __builtin_amdgcn_mfma_f32_16x16x32_bf16(qf[1], b1, sacc[ni], 0, 0, 0);
    }

    // scale + mask
#pragma unroll
    for (int ni = 0; ni < 4; ni++) {
      int col = kt * 64 + ni * 16 + lo;
#pragma unroll
      for (int r = 0; r < 4; r++) {
        float sv = sacc[ni][r] * 0.125f;
        if (mask[(size_t)(rowb + r) * S + col] == 0) sv = -1e9f;
        sacc[ni][r] = sv;
      }
    }

    // online softmax
    float mnew[4], alpha[4];
#pragma unroll
    for (int r = 0; r < 4; r++) {
      float tm = fmaxf(fmaxf(sacc[0][r], sacc[1][r]), fmaxf(sacc[2][r], sacc[3][r]));
      tm = fmaxf(tm, __shfl_xor(tm, 1));
      tm = fmaxf(tm, __shfl_xor(tm, 2));
      tm = fmaxf(tm, __shfl_xor(tm, 4));
      tm = fmaxf(tm, __shfl_xor(tm, 8));
      mnew[r] = fmaxf(m_i[r], tm);
      alpha[r] = __expf(m_i[r] - mnew[r]);
    }
#pragma unroll
    for (int r = 0; r < 4; r++) {
      float rs = 0.f;
#pragma unroll
      for (int ni = 0; ni < 4; ni++) {
        float p = __expf(sacc[ni][r] - mnew[r]);
        sacc[ni][r] = p;
        rs += p;
      }
      rs += __shfl_xor(rs, 1);
      rs += __shfl_xor(rs, 2);
      rs += __shfl_xor(rs, 4);
      rs += __shfl_xor(rs, 8);
      l_i[r] = l_i[r] * alpha[r] + rs;
      m_i[r] = mnew[r];
    }

    // P -> LDS (C-layout -> A-layout round trip)
#pragma unroll
    for (int ni = 0; ni < 4; ni++)
#pragma unroll
      for (int r = 0; r < 4; r++)
        Ps[(wv * 16 + quad * 4 + r) * LDV + ni * 16 + lo] = (bf16)sacc[ni][r];

    __syncthreads();  // Vt staged + Ps visible

    // rescale O, then O += P V
#pragma unroll
    for (int ni = 0; ni < 4; ni++)
#pragma unroll
      for (int r = 0; r < 4; r++) Oacc[ni][r] *= alpha[r];

#pragma unroll
    for (int kk = 0; kk < 2; kk++) {
      bf16x8 a = *(const bf16x8*)&Ps[(wv * 16 + lo) * LDV + kk * 32 + quad * 8];
#pragma unroll
      for (int ni = 0; ni < 4; ni++) {
        bf16x8 b = *(const bf16x8*)&Vt[(ni * 16 + lo) * LDV + kk * 32 + quad * 8];
        Oacc[ni] = __builtin_amdgcn_mfma_f32_16x16x32_bf16(a, b, Oacc[ni], 0, 0, 0);
      }
    }
    __syncthreads();  // before next V restage
  }

  // epilogue: normalize, write fp32 [B,S,D]
  const int b = bh >> 4, h = bh & (H - 1);
#pragma unroll
  for (int ni = 0; ni < 4; ni++)
#pragma unroll
    for (int r = 0; r < 4; r++) {
      int srow = qt * 64 + wv * 16 + quad * 4 + r;
      Og[(size_t)(b * S + srow) * D + h * DH + ni * 16 + lo] =
          Oacc[ni][r] / l_i[r];
    }
}

// ------------------------- launch -------------------------
extern "C" void kernel_launch(void* const* d_in, const int* in_sizes, int n_in,
                              void* d_out, int out_size, void* d_ws,
                              size_t ws_size, hipStream_t stream) {
  const float* q = (const float*)d_in[0];
  const float* k = (const float*)d_in[1];
  const float* v = (const float*)d_in[2];
  const int* mask = (const int*)d_in[3];
  const float* w_q = (const float*)d_in[4];
  const float* b_q = (const float*)d_in[5];
  const float* w_k = (const float*)d_in[6];
  const float* b_k = (const float*)d_in[7];
  const float* w_v = (const float*)d_in[8];
  const float* b_v = (const float*)d_in[9];
  const float* w_o = (const float*)d_in[10];
  const float* b_o = (const float*)d_in[11];

  // workspace layout: Qb/Kb/Vb bf16 [32,2048,64] (8MB each), AO fp32 (16MB)
  bf16* Qb = (bf16*)d_ws;
  bf16* Kb = Qb + (size_t)32 * S * DH;
  bf16* Vb = Kb + (size_t)32 * S * DH;
  float* AO = (float*)(Vb + (size_t)32 * S * DH);

  dim3 blk(256);
  dim3 gg(1024 / BN, M / BM);  // (16, 64)
  gemm_split<1><<<gg, blk, 0, stream>>>(q, w_q, b_q, (void*)Qb);
  gemm_split<1><<<gg, blk, 0, stream>>>(k, w_k, b_k, (void*)Kb);
  gemm_split<1><<<gg, blk, 0, stream>>>(v, w_v, b_v, (void*)Vb);

  attn_kernel<<<dim3(S / 64, 32), blk, 0, stream>>>(Qb, Kb, Vb, mask, AO);

  gemm_split<0><<<gg, blk, 0, stream>>>(AO, w_o, b_o, d_out);
}

// Round 2
// 434.423 us; speedup vs baseline: 1.1908x; 1.1908x over previous
//
#include <hip/hip_runtime.h>
#include <stdint.h>

typedef __bf16 bf16;
typedef __attribute__((ext_vector_type(4))) __bf16 bf16x4;
typedef __attribute__((ext_vector_type(8))) __bf16 bf16x8;
typedef __attribute__((ext_vector_type(4))) float f32x4;

// Problem dims (fixed)
constexpr int S = 2048;
constexpr int D = 1024;
constexpr int H = 16;
constexpr int DH = 64;
constexpr int M = 4096;  // B*S

constexpr float QSCALE = 0.18033688011112042f;  // 0.125 * log2(e)

// ------------------------- split-bf16 GEMM -------------------------
// C[M,1024] = A[M,1024] @ W[1024,1024] + bias ; A fp32 split hi/lo bf16.
constexpr int BM = 64, BN = 64, BK = 32;
constexpr int LDT = BK + 8;  // 40 elems

// OUT_MODE 0: fp32 row-major; 1: bf16 [B,H,S,DH] (with oscale); 2: bf16 V^T [B*H,DH,S]
template <int OUT_MODE>
__global__ __launch_bounds__(256) void gemm_split(
    const float* __restrict__ A, const float* __restrict__ W,
    const float* __restrict__ bias, void* __restrict__ out, float oscale) {
  __shared__ bf16 smem[4 * BM * LDT];
  bf16* Ah = smem;
  bf16* Al = smem + BM * LDT;
  bf16* Bh = smem + 2 * BM * LDT;
  bf16* Bl = smem + 3 * BM * LDT;

  const int tid = threadIdx.x;
  const int bn = blockIdx.x * BN;
  const int bm = blockIdx.y * BM;
  const int wv = tid >> 6;
  const int lane = tid & 63;
  const int quad = lane >> 4;
  const int lo = lane & 15;
  const int wm = (wv >> 1) * 32;
  const int wn = (wv & 1) * 32;

  f32x4 acc[2][2];
#pragma unroll
  for (int i = 0; i < 2; i++)
#pragma unroll
    for (int j = 0; j < 2; j++) acc[i][j] = {0.f, 0.f, 0.f, 0.f};

  const int ar = tid >> 2;
  const int ak = (tid & 3) * 8;
  const int bnn = tid & 63;
  const int bk0 = (tid >> 6) * 8;

  for (int kt = 0; kt < 1024 / BK; ++kt) {
    {
      const float* ap = A + (size_t)(bm + ar) * 1024 + kt * BK + ak;
      f32x4 a0 = *(const f32x4*)ap;
      f32x4 a1 = *(const f32x4*)(ap + 4);
      bf16x8 h, l;
#pragma unroll
      for (int j = 0; j < 4; j++) {
        float v0 = a0[j];
        bf16 h0 = (bf16)v0;
        h[j] = h0;
        l[j] = (bf16)(v0 - (float)h0);
        float v1 = a1[j];
        bf16 h1 = (bf16)v1;
        h[j + 4] = h1;
        l[j + 4] = (bf16)(v1 - (float)h1);
      }
      *(bf16x8*)&Ah[ar * LDT + ak] = h;
      *(bf16x8*)&Al[ar * LDT + ak] = l;
    }
    {
      const float* wp = W + (size_t)(kt * BK + bk0) * 1024 + bn + bnn;
      bf16x8 h, l;
#pragma unroll
      for (int j = 0; j < 8; j++) {
        float v0 = wp[(size_t)j * 1024];
        bf16 h0 = (bf16)v0;
        h[j] = h0;
        l[j] = (bf16)(v0 - (float)h0);
      }
      *(bf16x8*)&Bh[bnn * LDT + bk0] = h;
      *(bf16x8*)&Bl[bnn * LDT + bk0] = l;
    }
    __syncthreads();

    bf16x8 afh[2], afl[2], bfh[2], bfl[2];
#pragma unroll
    for (int mi = 0; mi < 2; mi++) {
      afh[mi] = *(const bf16x8*)&Ah[(wm + mi * 16 + lo) * LDT + quad * 8];
      afl[mi] = *(const bf16x8*)&Al[(wm + mi * 16 + lo) * LDT + quad * 8];
    }
#pragma unroll
    for (int ni = 0; ni < 2; ni++) {
      bfh[ni] = *(const bf16x8*)&Bh[(wn + ni * 16 + lo) * LDT + quad * 8];
      bfl[ni] = *(const bf16x8*)&Bl[(wn + ni * 16 + lo) * LDT + quad * 8];
    }
#pragma unroll
    for (int mi = 0; mi < 2; mi++)
#pragma unroll
      for (int ni = 0; ni < 2; ni++) {
        acc[mi][ni] = __builtin_amdgcn_mfma_f32_16x16x32_bf16(
            afh[mi], bfh[ni], acc[mi][ni], 0, 0, 0);
        acc[mi][ni] = __builtin_amdgcn_mfma_f32_16x16x32_bf16(
            afh[mi], bfl[ni], acc[mi][ni], 0, 0, 0);
        acc[mi][ni] = __builtin_amdgcn_mfma_f32_16x16x32_bf16(
            afl[mi], bfh[ni], acc[mi][ni], 0, 0, 0);
      }
    __syncthreads();
  }

  if (OUT_MODE == 2) {
    // bf16 V^T epilogue: LDS transpose (reuses smem), coalesced store.
    bf16* T = smem;  // [64][72]
#pragma unroll
    for (int mi = 0; mi < 2; mi++)
#pragma unroll
      for (int ni = 0; ni < 2; ni++) {
        int col = wn + ni * 16 + lo;
        float bv = bias[bn + col];
        bf16x4 t;
#pragma unroll
        for (int r = 0; r < 4; r++) t[r] = (bf16)((acc[mi][ni][r] + bv) * oscale);
        *(bf16x4*)&T[col * 72 + wm + mi * 16 + quad * 4] = t;
      }
    __syncthreads();
    const int dh = tid >> 2, sc = (tid & 3) * 16;
    bf16x8 r0 = *(const bf16x8*)&T[dh * 72 + sc];
    bf16x8 r1 = *(const bf16x8*)&T[dh * 72 + sc + 8];
    const int b = bm >> 11, h = blockIdx.x;
    bf16* gp = (bf16*)out + ((size_t)(b * H + h) * DH + dh) * S + (bm & (S - 1)) + sc;
    *(bf16x8*)gp = r0;
    *(bf16x8*)(gp + 8) = r1;
    return;
  }

#pragma unroll
  for (int mi = 0; mi < 2; mi++)
#pragma unroll
    for (int ni = 0; ni < 2; ni++) {
      int col = bn + wn + ni * 16 + lo;
      float bv = bias[col];
#pragma unroll
      for (int r = 0; r < 4; r++) {
        int row = bm + wm + mi * 16 + quad * 4 + r;
        float v = (acc[mi][ni][r] + bv) * oscale;
        if (OUT_MODE == 0) {
          ((float*)out)[(size_t)row * 1024 + col] = v;
        } else {
          int b = row >> 11, s = row & (S - 1);
          int h = col >> 6, dh = col & (DH - 1);
          ((bf16*)out)[((((size_t)b * H + h) * S + s) << 6) + dh] = (bf16)v;
        }
      }
    }
}

// ------------------------- mask -> bitmask -------------------------
// MB[kt][q] bit t = (mask[q][kt*64+t] != 0)
__global__ __launch_bounds__(256) void maskbits_kernel(
    const int* __restrict__ mask, uint64_t* __restrict__ MB) {
  const int gid = blockIdx.x * 4 + (threadIdx.x >> 6);
  const int lane = threadIdx.x & 63;
  const int kt = gid >> 11;
  const int q = gid & (S - 1);
  int v = mask[(size_t)q * S + kt * 64 + lane];
  uint64_t bits = __ballot(v != 0);
  if (lane == 0) MB[(size_t)kt * S + q] = bits;
}

// ------------------------- flash attention (barrier-free) -------------------------
// Q pre-scaled by 0.125*log2e. S^T = K Q^T so each lane's column = one query row.
// No-max softmax: p = bit ? exp2(s) : 0. Per-wave private P transpose in LDS.
constexpr int LDP = 72;  // P row stride (144B, 16B-aligned)

__global__ __launch_bounds__(256) void attn_kernel(
    const bf16* __restrict__ Qg, const bf16* __restrict__ Kg,
    const bf16* __restrict__ VTg, const uint64_t* __restrict__ MB,
    float* __restrict__ Og) {
  __shared__ bf16 Ps[4][32 * LDP];

  const int tid = threadIdx.x;
  const int wv = tid >> 6;
  const int lane = tid & 63;
  const int quad = lane >> 4;
  const int lo = lane & 15;

  // XCD-aware swizzle: XCD x (lin%8) owns bh in {4x..4x+3} -> 2MB K+V set in its L2
  const int lin = blockIdx.x;
  const int bh = (lin & 7) * 4 + ((lin >> 3) & 3);
  const int qt = lin >> 5;  // 0..15 (128 q-rows per block)
  const int qbase = qt * 128 + wv * 32;
  const size_t base = (size_t)bh * S * DH;
  bf16* Pw = Ps[wv];

  // Q B-frags: [nq][kk], q = qbase + nq*16 + lo, dh = kk*32 + quad*8 + j
  bf16x8 qf[2][2];
#pragma unroll
  for (int nq = 0; nq < 2; nq++) {
    const bf16* qp = Qg + base + (size_t)(qbase + nq * 16 + lo) * DH + quad * 8;
    qf[nq][0] = *(const bf16x8*)qp;
    qf[nq][1] = *(const bf16x8*)(qp + 32);
  }

  f32x4 Oacc[2][4];
#pragma unroll
  for (int i = 0; i < 2; i++)
#pragma unroll
    for (int j = 0; j < 4; j++) Oacc[i][j] = {0.f, 0.f, 0.f, 0.f};
  float lpart[2] = {0.f, 0.f};

  for (int kt = 0; kt < S / 64; ++kt) {
    // mask words for this lane's two query rows
    uint64_t m0 = MB[(size_t)kt * S + qbase + lo] >> (quad * 4);
    uint64_t m1 = MB[(size_t)kt * S + qbase + 16 + lo] >> (quad * 4);
    uint32_t mw[2][2] = {{(uint32_t)m0, (uint32_t)(m0 >> 32)},
                         {(uint32_t)m1, (uint32_t)(m1 >> 32)}};

    // S^T tile: A = K[key][dh] straight from global, B = Q frags
    f32x4 sacc[4][2];
#pragma unroll
    for (int mi = 0; mi < 4; mi++)
#pragma unroll
      for (int nq = 0; nq < 2; nq++) sacc[mi][nq] = {0.f, 0.f, 0.f, 0.f};
#pragma unroll
    for (int mi = 0; mi < 4; mi++) {
      const bf16* kp = Kg + base + (size_t)(kt * 64 + mi * 16 + lo) * DH + quad * 8;
      bf16x8 k0 = *(const bf16x8*)kp;
      bf16x8 k1 = *(const bf16x8*)(kp + 32);
#pragma unroll
      for (int nq = 0; nq < 2; nq++) {
        sacc[mi][nq] = __builtin_amdgcn_mfma_f32_16x16x32_bf16(k0, qf[nq][0], sacc[mi][nq], 0, 0, 0);
        sacc[mi][nq] = __builtin_amdgcn_mfma_f32_16x16x32_bf16(k1, qf[nq][1], sacc[mi][nq], 0, 0, 0);
      }
    }

    // p = bit ? exp2(s) : 0 ; accumulate row-sums; pack P -> per-wave LDS
#pragma unroll
    for (int mi = 0; mi < 4; mi++)
#pragma unroll
      for (int nq = 0; nq < 2; nq++) {
        bf16x4 t;
#pragma unroll
        for (int r = 0; r < 4; r++) {
          float p = exp2f(sacc[mi][nq][r]);
          p = ((mw[nq][mi >> 1] >> (((mi & 1) << 4) + r)) & 1) ? p : 0.0f;
          lpart[nq] += p;
          t[r] = (bf16)p;
        }
        *(bf16x4*)&Pw[(nq * 16 + lo) * LDP + mi * 16 + quad * 4] = t;
      }

    // O += P V  (A = P from LDS, B = V^T frags straight from global)
#pragma unroll
    for (int kk = 0; kk < 2; kk++) {
      bf16x8 pa0 = *(const bf16x8*)&Pw[lo * LDP + kk * 32 + quad * 8];
      bf16x8 pa1 = *(const bf16x8*)&Pw[(16 + lo) * LDP + kk * 32 + quad * 8];
#pragma unroll
      for (int ni = 0; ni < 4; ni++) {
        bf16x8 vb = *(const bf16x8*)(VTg + ((size_t)bh * DH + ni * 16 + lo) * S +
                                     kt * 64 + kk * 32 + quad * 8);
        Oacc[0][ni] = __builtin_amdgcn_mfma_f32_16x16x32_bf16(pa0, vb, Oacc[0][ni], 0, 0, 0);
        Oacc[1][ni] = __builtin_amdgcn_mfma_f32_16x16x32_bf16(pa1, vb, Oacc[1][ni], 0, 0, 0);
      }
    }
  }

  // finish row-sums across quads (keys were split 16/quad)
#pragma unroll
  for (int nq = 0; nq < 2; nq++) {
    lpart[nq] += __shfl_xor(lpart[nq], 16);
    lpart[nq] += __shfl_xor(lpart[nq], 32);
  }

  const int b = bh >> 4, h = bh & (H - 1);
#pragma unroll
  for (int qmi = 0; qmi < 2; qmi++)
#pragma unroll
    for (int r = 0; r < 4; r++) {
      float inv = 1.0f / __shfl(lpart[qmi], quad * 4 + r);
      int q = qbase + qmi * 16 + quad * 4 + r;
#pragma unroll
      for (int ni = 0; ni < 4; ni++)
        Og[(size_t)(b * S + q) * D + h * DH + ni * 16 + lo] = Oacc[qmi][ni][r] * inv;
    }
}

// ------------------------- launch -------------------------
extern "C" void kernel_launch(void* const* d_in, const int* in_sizes, int n_in,
                              void* d_out, int out_size, void* d_ws,
                              size_t ws_size, hipStream_t stream) {
  const float* q = (const float*)d_in[0];
  const float* k = (const float*)d_in[1];
  const float* v = (const float*)d_in[2];
  const int* mask = (const int*)d_in[3];
  const float* w_q = (const float*)d_in[4];
  const float* b_q = (const float*)d_in[5];
  const float* w_k = (const float*)d_in[6];
  const float* b_k = (const float*)d_in[7];
  const float* w_v = (const float*)d_in[8];
  const float* b_v = (const float*)d_in[9];
  const float* w_o = (const float*)d_in[10];
  const float* b_o = (const float*)d_in[11];

  // ws: Qb 8MB | Kb 8MB | VT 8MB | AO 16MB | MB 0.5MB
  bf16* Qb = (bf16*)d_ws;
  bf16* Kb = Qb + (size_t)32 * S * DH;
  bf16* VT = Kb + (size_t)32 * S * DH;
  float* AO = (float*)(VT + (size_t)32 * S * DH);
  uint64_t* MB = (uint64_t*)(AO + (size_t)M * D);

  dim3 blk(256);
  dim3 gg(1024 / BN, M / BM);  // (16, 64)

  maskbits_kernel<<<16384, blk, 0, stream>>>(mask, MB);
  gemm_split<1><<<gg, blk, 0, stream>>>(q, w_q, b_q, (void*)Qb, QSCALE);
  gemm_split<1><<<gg, blk, 0, stream>>>(k, w_k, b_k, (void*)Kb, 1.0f);
  gemm_split<2><<<gg, blk, 0, stream>>>(v, w_v, b_v, (void*)VT, 1.0f);

  attn_kernel<<<dim3(512), blk, 0, stream>>>(Qb, Kb, VT, MB, AO);

  gemm_split<0><<<gg, blk, 0, stream>>>(AO, w_o, b_o, d_out, 1.0f);
}

// Round 3
// 366.035 us; speedup vs baseline: 1.4132x; 1.1868x over previous
//
#include <hip/hip_runtime.h>
#include <stdint.h>

typedef __bf16 bf16;
typedef __attribute__((ext_vector_type(4))) __bf16 bf16x4;
typedef __attribute__((ext_vector_type(8))) __bf16 bf16x8;
typedef __attribute__((ext_vector_type(4))) float f32x4;

constexpr int S = 2048;
constexpr int D = 1024;
constexpr int H = 16;
constexpr int DH = 64;
constexpr int M = 4096;  // B*S

constexpr float QSCALE = 0.18033688011112042f;  // 0.125 * log2(e)

// ===================== fused QKV GEMM: 128x128 tile, split-bf16 =====================
// C = A @ W + bias ; A fp32 -> hi/lo bf16 in LDS; 3 MFMAs per (h,l) pair.
// z=0: Q -> bf16 [B,H,S,DH] * QSCALE ; z=1: K -> bf16 [B,H,S,DH] ; z=2: V^T -> bf16 [B*H,DH,S]
constexpr int LDT = 40;  // 32 + 8 pad (80B rows, 16B aligned)

__global__ __launch_bounds__(256, 3) void gemm_qkv(
    const float* __restrict__ Aq, const float* __restrict__ Ak,
    const float* __restrict__ Av, const float* __restrict__ Wq,
    const float* __restrict__ Wk, const float* __restrict__ Wv,
    const float* __restrict__ bq, const float* __restrict__ bk,
    const float* __restrict__ bv, bf16* __restrict__ Qb,
    bf16* __restrict__ Kb, bf16* __restrict__ VT) {
  __shared__ bf16 smem[4 * 128 * LDT];  // Ah Al Bh Bl : 40960 B
  bf16* Ah = smem;
  bf16* Al = smem + 128 * LDT;
  bf16* Bh = smem + 2 * 128 * LDT;
  bf16* Bl = smem + 3 * 128 * LDT;

  const int z = blockIdx.z;
  const float* A = (z == 0) ? Aq : (z == 1) ? Ak : Av;
  const float* W = (z == 0) ? Wq : (z == 1) ? Wk : Wv;
  const float* bias = (z == 0) ? bq : (z == 1) ? bk : bv;
  const float oscale = (z == 0) ? QSCALE : 1.0f;

  const int tid = threadIdx.x;
  const int bn = blockIdx.x * 128;
  const int bm = blockIdx.y * 128;
  const int wv = tid >> 6;
  const int lane = tid & 63;
  const int quad = lane >> 4;
  const int lo = lane & 15;
  const int wm = (wv >> 1) * 64;
  const int wn = (wv & 1) * 64;

  f32x4 acc[4][4];
#pragma unroll
  for (int i = 0; i < 4; i++)
#pragma unroll
    for (int j = 0; j < 4; j++) acc[i][j] = {0.f, 0.f, 0.f, 0.f};

  const int ar0 = tid >> 2;        // rows {ar0, ar0+64}
  const int ak = (tid & 3) * 8;    // k offset
  const int bnn = tid & 127;       // B: n
  const int bk0 = (tid >> 7) * 16; // B: k base (0 or 16)

  for (int kt = 0; kt < 1024 / 32; ++kt) {
    // ---- stage A (128x32 fp32 -> hi/lo) ----
#pragma unroll
    for (int rb = 0; rb < 2; rb++) {
      const int rr = ar0 + rb * 64;
      const float* ap = A + (size_t)(bm + rr) * 1024 + kt * 32 + ak;
      f32x4 a0 = *(const f32x4*)ap;
      f32x4 a1 = *(const f32x4*)(ap + 4);
      bf16x8 h, l;
#pragma unroll
      for (int j = 0; j < 4; j++) {
        float v0 = a0[j];
        bf16 h0 = (bf16)v0;
        h[j] = h0;
        l[j] = (bf16)(v0 - (float)h0);
        float v1 = a1[j];
        bf16 h1 = (bf16)v1;
        h[j + 4] = h1;
        l[j + 4] = (bf16)(v1 - (float)h1);
      }
      *(bf16x8*)&Ah[rr * LDT + ak] = h;
      *(bf16x8*)&Al[rr * LDT + ak] = l;
    }
    // ---- stage B transposed ([n][k], 32x128 fp32 -> hi/lo) ----
    {
      const float* wp = W + (size_t)(kt * 32 + bk0) * 1024 + bn + bnn;
      bf16x8 h[2], l[2];
#pragma unroll
      for (int g = 0; g < 2; g++)
#pragma unroll
        for (int j = 0; j < 8; j++) {
          float v0 = wp[(size_t)(g * 8 + j) * 1024];
          bf16 h0 = (bf16)v0;
          h[g][j] = h0;
          l[g][j] = (bf16)(v0 - (float)h0);
        }
      *(bf16x8*)&Bh[bnn * LDT + bk0] = h[0];
      *(bf16x8*)&Bh[bnn * LDT + bk0 + 8] = h[1];
      *(bf16x8*)&Bl[bnn * LDT + bk0] = l[0];
      *(bf16x8*)&Bl[bnn * LDT + bk0 + 8] = l[1];
    }
    __syncthreads();

    bf16x8 afh[4], afl[4], bfh[4], bfl[4];
#pragma unroll
    for (int mi = 0; mi < 4; mi++) {
      afh[mi] = *(const bf16x8*)&Ah[(wm + mi * 16 + lo) * LDT + quad * 8];
      afl[mi] = *(const bf16x8*)&Al[(wm + mi * 16 + lo) * LDT + quad * 8];
    }
#pragma unroll
    for (int ni = 0; ni < 4; ni++) {
      bfh[ni] = *(const bf16x8*)&Bh[(wn + ni * 16 + lo) * LDT + quad * 8];
      bfl[ni] = *(const bf16x8*)&Bl[(wn + ni * 16 + lo) * LDT + quad * 8];
    }
#pragma unroll
    for (int mi = 0; mi < 4; mi++)
#pragma unroll
      for (int ni = 0; ni < 4; ni++) {
        acc[mi][ni] = __builtin_amdgcn_mfma_f32_16x16x32_bf16(afh[mi], bfh[ni], acc[mi][ni], 0, 0, 0);
        acc[mi][ni] = __builtin_amdgcn_mfma_f32_16x16x32_bf16(afh[mi], bfl[ni], acc[mi][ni], 0, 0, 0);
        acc[mi][ni] = __builtin_amdgcn_mfma_f32_16x16x32_bf16(afl[mi], bfh[ni], acc[mi][ni], 0, 0, 0);
      }
    __syncthreads();
  }

  const int b = bm >> 11;
  const int srow0 = bm & (S - 1);

  if (z == 2) {
    // V^T: direct 8B stores, [bh][dh][s]
#pragma unroll
    for (int mi = 0; mi < 4; mi++)
#pragma unroll
      for (int ni = 0; ni < 4; ni++) {
        int col = bn + wn + ni * 16 + lo;  // 0..1023
        int h = col >> 6, dh = col & 63;
        float bvv = bias[col];
        bf16x4 t;
#pragma unroll
        for (int r = 0; r < 4; r++) t[r] = (bf16)(acc[mi][ni][r] + bvv);
        int s0 = srow0 + wm + mi * 16 + quad * 4;
        *(bf16x4*)&VT[(((size_t)(b * H + h)) * DH + dh) * S + s0] = t;
      }
    return;
  }

  // Q/K: LDS transpose for coalesced [bh][s][dh] stores
  bf16* T = smem;  // [128][136]
  __syncthreads();
#pragma unroll
  for (int mi = 0; mi < 4; mi++)
#pragma unroll
    for (int ni = 0; ni < 4; ni++) {
      int col = wn + ni * 16 + lo;
      float bvv = bias[bn + col];
#pragma unroll
      for (int r = 0; r < 4; r++) {
        int row = wm + mi * 16 + quad * 4 + r;
        T[row * 136 + col] = (bf16)((acc[mi][ni][r] + bvv) * oscale);
      }
    }
  __syncthreads();
  bf16* out = (z == 0) ? Qb : Kb;
  const int rr = tid >> 1;
  const int half = tid & 1;
  const int h = (bn >> 6) + half;
  bf16* gp = out + (((size_t)(b * H + h)) * S + srow0 + rr) * DH;
#pragma unroll
  for (int j = 0; j < 8; j++)
    *(bf16x8*)(gp + j * 8) = *(const bf16x8*)&T[rr * 136 + half * 64 + j * 8];
}

// ===================== O-projection GEMM: 128x64 tile, split-bf16, fp32 out ==========
__global__ __launch_bounds__(256, 3) void gemm_o(
    const float* __restrict__ A, const float* __restrict__ W,
    const float* __restrict__ bias, float* __restrict__ out) {
  __shared__ bf16 smem[(128 + 128 + 64 + 64) * LDT];
  bf16* Ah = smem;
  bf16* Al = smem + 128 * LDT;
  bf16* Bh = smem + 2 * 128 * LDT;
  bf16* Bl = smem + 2 * 128 * LDT + 64 * LDT;

  const int tid = threadIdx.x;
  const int bn = blockIdx.x * 64;
  const int bm = blockIdx.y * 128;
  const int wv = tid >> 6;
  const int lane = tid & 63;
  const int quad = lane >> 4;
  const int lo = lane & 15;
  const int wm = (wv >> 1) * 64;
  const int wn = (wv & 1) * 32;

  f32x4 acc[4][2];
#pragma unroll
  for (int i = 0; i < 4; i++)
#pragma unroll
    for (int j = 0; j < 2; j++) acc[i][j] = {0.f, 0.f, 0.f, 0.f};

  const int ar0 = tid >> 2;
  const int ak = (tid & 3) * 8;
  const int bnn = tid & 63;
  const int bk0 = (tid >> 6) * 8;

  for (int kt = 0; kt < 1024 / 32; ++kt) {
#pragma unroll
    for (int rb = 0; rb < 2; rb++) {
      const int rr = ar0 + rb * 64;
      const float* ap = A + (size_t)(bm + rr) * 1024 + kt * 32 + ak;
      f32x4 a0 = *(const f32x4*)ap;
      f32x4 a1 = *(const f32x4*)(ap + 4);
      bf16x8 h, l;
#pragma unroll
      for (int j = 0; j < 4; j++) {
        float v0 = a0[j];
        bf16 h0 = (bf16)v0;
        h[j] = h0;
        l[j] = (bf16)(v0 - (float)h0);
        float v1 = a1[j];
        bf16 h1 = (bf16)v1;
        h[j + 4] = h1;
        l[j + 4] = (bf16)(v1 - (float)h1);
      }
      *(bf16x8*)&Ah[rr * LDT + ak] = h;
      *(bf16x8*)&Al[rr * LDT + ak] = l;
    }
    {
      const float* wp = W + (size_t)(kt * 32 + bk0) * 1024 + bn + bnn;
      bf16x8 h, l;
#pragma unroll
      for (int j = 0; j < 8; j++) {
        float v0 = wp[(size_t)j * 1024];
        bf16 h0 = (bf16)v0;
        h[j] = h0;
        l[j] = (bf16)(v0 - (float)h0);
      }
      *(bf16x8*)&Bh[bnn * LDT + bk0] = h;
      *(bf16x8*)&Bl[bnn * LDT + bk0] = l;
    }
    __syncthreads();

    bf16x8 afh[4], afl[4], bfh[2], bfl[2];
#pragma unroll
    for (int mi = 0; mi < 4; mi++) {
      afh[mi] = *(const bf16x8*)&Ah[(wm + mi * 16 + lo) * LDT + quad * 8];
      afl[mi] = *(const bf16x8*)&Al[(wm + mi * 16 + lo) * LDT + quad * 8];
    }
#pragma unroll
    for (int ni = 0; ni < 2; ni++) {
      bfh[ni] = *(const bf16x8*)&Bh[(wn + ni * 16 + lo) * LDT + quad * 8];
      bfl[ni] = *(const bf16x8*)&Bl[(wn + ni * 16 + lo) * LDT + quad * 8];
    }
#pragma unroll
    for (int mi = 0; mi < 4; mi++)
#pragma unroll
      for (int ni = 0; ni < 2; ni++) {
        acc[mi][ni] = __builtin_amdgcn_mfma_f32_16x16x32_bf16(afh[mi], bfh[ni], acc[mi][ni], 0, 0, 0);
        acc[mi][ni] = __builtin_amdgcn_mfma_f32_16x16x32_bf16(afh[mi], bfl[ni], acc[mi][ni], 0, 0, 0);
        acc[mi][ni] = __builtin_amdgcn_mfma_f32_16x16x32_bf16(afl[mi], bfh[ni], acc[mi][ni], 0, 0, 0);
      }
    __syncthreads();
  }

#pragma unroll
  for (int mi = 0; mi < 4; mi++)
#pragma unroll
    for (int ni = 0; ni < 2; ni++) {
      int col = bn + wn + ni * 16 + lo;
      float bvv = bias[col];
#pragma unroll
      for (int r = 0; r < 4; r++) {
        int row = bm + wm + mi * 16 + quad * 4 + r;
        out[(size_t)row * 1024 + col] = acc[mi][ni][r] + bvv;
      }
    }
}

// ===================== mask -> bitmask =====================
__global__ __launch_bounds__(256) void maskbits_kernel(
    const int* __restrict__ mask, uint64_t* __restrict__ MB) {
  const int gid = blockIdx.x * 4 + (threadIdx.x >> 6);
  const int lane = threadIdx.x & 63;
  const int kt = gid >> 11;
  const int q = gid & (S - 1);
  int v = mask[(size_t)q * S + kt * 64 + lane];
  uint64_t bits = __ballot(v != 0);
  if (lane == 0) MB[(size_t)kt * S + q] = bits;
}

// ===================== attention: 8 waves, key-split x2, barrier-free loop ============
constexpr int LDP = 72;

__global__ __launch_bounds__(512, 4) void attn_kernel(
    const bf16* __restrict__ Qg, const bf16* __restrict__ Kg,
    const bf16* __restrict__ VTg, const uint64_t* __restrict__ MB,
    float* __restrict__ Og) {
  __shared__ bf16 Ps[8][32 * LDP];  // 36864 B; reused as combine buffer

  const int tid = threadIdx.x;
  const int wv = tid >> 6;
  const int lane = tid & 63;
  const int quad = lane >> 4;
  const int lo = lane & 15;
  const int ks = wv >> 2;   // key-split half
  const int wq = wv & 3;    // q-group within block

  const int lin = blockIdx.x;  // 512 blocks
  const int bh = (lin & 7) * 4 + ((lin >> 3) & 3);  // XCD-local K/V set
  const int qt = lin >> 5;
  const int qbase = qt * 128 + wq * 32;
  const size_t base = (size_t)bh * S * DH;
  bf16* Pw = Ps[wv];

  bf16x8 qf[2][2];
#pragma unroll
  for (int nq = 0; nq < 2; nq++) {
    const bf16* qp = Qg + base + (size_t)(qbase + nq * 16 + lo) * DH + quad * 8;
    qf[nq][0] = *(const bf16x8*)qp;
    qf[nq][1] = *(const bf16x8*)(qp + 32);
  }

  f32x4 Oacc[2][4];
#pragma unroll
  for (int i = 0; i < 2; i++)
#pragma unroll
    for (int j = 0; j < 4; j++) Oacc[i][j] = {0.f, 0.f, 0.f, 0.f};
  float lpart[2] = {0.f, 0.f};

  for (int kt = ks * 16; kt < ks * 16 + 16; ++kt) {
    uint64_t m0 = MB[(size_t)kt * S + qbase + lo] >> (quad * 4);
    uint64_t m1 = MB[(size_t)kt * S + qbase + 16 + lo] >> (quad * 4);
    uint32_t mw[2][2] = {{(uint32_t)m0, (uint32_t)(m0 >> 32)},
                         {(uint32_t)m1, (uint32_t)(m1 >> 32)}};

    f32x4 sacc[4][2];
#pragma unroll
    for (int mi = 0; mi < 4; mi++)
#pragma unroll
      for (int nq = 0; nq < 2; nq++) sacc[mi][nq] = {0.f, 0.f, 0.f, 0.f};
#pragma unroll
    for (int mi = 0; mi < 4; mi++) {
      const bf16* kp = Kg + base + (size_t)(kt * 64 + mi * 16 + lo) * DH + quad * 8;
      bf16x8 k0 = *(const bf16x8*)kp;
      bf16x8 k1 = *(const bf16x8*)(kp + 32);
#pragma unroll
      for (int nq = 0; nq < 2; nq++) {
        sacc[mi][nq] = __builtin_amdgcn_mfma_f32_16x16x32_bf16(k0, qf[nq][0], sacc[mi][nq], 0, 0, 0);
        sacc[mi][nq] = __builtin_amdgcn_mfma_f32_16x16x32_bf16(k1, qf[nq][1], sacc[mi][nq], 0, 0, 0);
      }
    }

#pragma unroll
    for (int mi = 0; mi < 4; mi++)
#pragma unroll
      for (int nq = 0; nq < 2; nq++) {
        bf16x4 t;
#pragma unroll
        for (int r = 0; r < 4; r++) {
          float p = exp2f(sacc[mi][nq][r]);
          p = ((mw[nq][mi >> 1] >> (((mi & 1) << 4) + r)) & 1) ? p : 0.0f;
          lpart[nq] += p;
          t[r] = (bf16)p;
        }
        *(bf16x4*)&Pw[(nq * 16 + lo) * LDP + mi * 16 + quad * 4] = t;
      }

#pragma unroll
    for (int kk = 0; kk < 2; kk++) {
      bf16x8 pa0 = *(const bf16x8*)&Pw[lo * LDP + kk * 32 + quad * 8];
      bf16x8 pa1 = *(const bf16x8*)&Pw[(16 + lo) * LDP + kk * 32 + quad * 8];
#pragma unroll
      for (int ni = 0; ni < 4; ni++) {
        bf16x8 vb = *(const bf16x8*)(VTg + ((size_t)bh * DH + ni * 16 + lo) * S +
                                     kt * 64 + kk * 32 + quad * 8);
        Oacc[0][ni] = __builtin_amdgcn_mfma_f32_16x16x32_bf16(pa0, vb, Oacc[0][ni], 0, 0, 0);
        Oacc[1][ni] = __builtin_amdgcn_mfma_f32_16x16x32_bf16(pa1, vb, Oacc[1][ni], 0, 0, 0);
      }
    }
  }

#pragma unroll
  for (int nq = 0; nq < 2; nq++) {
    lpart[nq] += __shfl_xor(lpart[nq], 16);
    lpart[nq] += __shfl_xor(lpart[nq], 32);
  }

  // combine the two key-split halves through LDS
  float* CB = (float*)Ps;  // 4 waves x 64 lanes x 36 floats = 36864 B
  __syncthreads();  // all waves done with Ps as P-buffer
  if (ks == 1) {
    float* p = CB + (size_t)(wq * 64 + lane) * 36;
#pragma unroll
    for (int qmi = 0; qmi < 2; qmi++)
#pragma unroll
      for (int ni = 0; ni < 4; ni++)
        *(f32x4*)(p + (qmi * 4 + ni) * 4) = Oacc[qmi][ni];
    p[32] = lpart[0];
    p[33] = lpart[1];
  }
  __syncthreads();
  if (ks == 0) {
    float* p = CB + (size_t)(wq * 64 + lane) * 36;
#pragma unroll
    for (int qmi = 0; qmi < 2; qmi++)
#pragma unroll
      for (int ni = 0; ni < 4; ni++) {
        f32x4 o = *(const f32x4*)(p + (qmi * 4 + ni) * 4);
#pragma unroll
        for (int r = 0; r < 4; r++) Oacc[qmi][ni][r] += o[r];
      }
    lpart[0] += p[32];
    lpart[1] += p[33];

    const int b = bh >> 4, h = bh & (H - 1);
#pragma unroll
    for (int qmi = 0; qmi < 2; qmi++)
#pragma unroll
      for (int r = 0; r < 4; r++) {
        float inv = 1.0f / __shfl(lpart[qmi], quad * 4 + r);
        int q = qbase + qmi * 16 + quad * 4 + r;
#pragma unroll
        for (int ni = 0; ni < 4; ni++)
          Og[(size_t)(b * S + q) * D + h * DH + ni * 16 + lo] = Oacc[qmi][ni][r] * inv;
      }
  }
}

// ===================== launch =====================
extern "C" void kernel_launch(void* const* d_in, const int* in_sizes, int n_in,
                              void* d_out, int out_size, void* d_ws,
                              size_t ws_size, hipStream_t stream) {
  const float* q = (const float*)d_in[0];
  const float* k = (const float*)d_in[1];
  const float* v = (const float*)d_in[2];
  const int* mask = (const int*)d_in[3];
  const float* w_q = (const float*)d_in[4];
  const float* b_q = (const float*)d_in[5];
  const float* w_k = (const float*)d_in[6];
  const float* b_k = (const float*)d_in[7];
  const float* w_v = (const float*)d_in[8];
  const float* b_v = (const float*)d_in[9];
  const float* w_o = (const float*)d_in[10];
  const float* b_o = (const float*)d_in[11];

  // ws: Qb 8MB | Kb 8MB | VT 8MB | AO 16MB | MB 0.5MB
  bf16* Qb = (bf16*)d_ws;
  bf16* Kb = Qb + (size_t)32 * S * DH;
  bf16* VT = Kb + (size_t)32 * S * DH;
  float* AO = (float*)(VT + (size_t)32 * S * DH);
  uint64_t* MB = (uint64_t*)(AO + (size_t)M * D);

  maskbits_kernel<<<16384, 256, 0, stream>>>(mask, MB);

  gemm_qkv<<<dim3(1024 / 128, M / 128, 3), 256, 0, stream>>>(
      q, k, v, w_q, w_k, w_v, b_q, b_k, b_v, Qb, Kb, VT);

  attn_kernel<<<dim3(512), 512, 0, stream>>>(Qb, Kb, VT, MB, AO);

  gemm_o<<<dim3(1024 / 64, M / 128), 256, 0, stream>>>(AO, w_o, b_o, (float*)d_out);
}